// Round 5
// baseline (348.398 us; speedup 1.0000x reference)
//
#include <hip/hip_runtime.h>
#include <stdint.h>

#define B_ 2
#define T_ 4096
#define D_ 512
#define H_ 8
#define DH_ 64

typedef __bf16 bf16;
typedef __bf16 bf16x4_t __attribute__((ext_vector_type(4)));
typedef __bf16 bf16x8_t __attribute__((ext_vector_type(8)));
typedef float f32x4 __attribute__((ext_vector_type(4)));
typedef short short4_t __attribute__((ext_vector_type(4)));
typedef uint32_t u32;

static constexpr float QSCALE = 0.18033688011112042f;   // log2(e)/8 (folded into Wq,bq)

__device__ __forceinline__ void async16(void* lds, const void* g) {
  __builtin_amdgcn_global_load_lds(
      (const __attribute__((address_space(1))) void*)g,
      (__attribute__((address_space(3))) void*)lds, 16, 0, 0);
}

// ---------------------------------------------------------------- prep ----
__global__ __launch_bounds__(256) void prep_kernel(
    const float* __restrict__ x,
    const float* __restrict__ Wq, const float* __restrict__ Wk,
    const float* __restrict__ Wv, const float* __restrict__ Wo,
    const void* __restrict__ maskp,
    bf16* __restrict__ xb, bf16* __restrict__ WTall, bf16* __restrict__ WoT,
    u32* __restrict__ bmask)
{
  int bid = blockIdx.x;
  int tid = threadIdx.x;
  if (bid < 4096) {
    int idx = bid * 256 + tid;
    const float4* xf = (const float4*)x;
    float4 v = xf[idx];
    bf16x4_t o;
    o[0] = (bf16)v.x; o[1] = (bf16)v.y; o[2] = (bf16)v.z; o[3] = (bf16)v.w;
    ((bf16x4_t*)xb)[idx] = o;
  } else if (bid < 8192) {
    int gid = (bid - 4096) * 256 + tid;
    int sel = gid >> 18;
    int idx = gid & 262143;
    int n = idx >> 9, k = idx & 511;
    if (sel < 3) {
      const float* W = (sel == 0) ? Wq : (sel == 1) ? Wk : Wv;
      float v = W[k * 512 + n];
      if (sel == 0) v *= QSCALE;
      WTall[gid] = (bf16)v;
    } else {
      WoT[idx] = (bf16)Wo[k * 512 + n];
    }
  } else {
    int wid = (bid - 8192) * 256 + tid;   // 524,288 words
    const uint8_t* m8 = (const uint8_t*)maskp;
    bool u8mode = (__ballot(m8[4 * (tid & 63) + 1] != 0) != 0ull);
    int row = wid >> 7, wcol = wid & 127;
    size_t off = (size_t)row * 4096 + (size_t)wcol * 32;
    u32 w = 0;
    if (u8mode) {
      const uint4* p = (const uint4*)(m8 + off);
      uint4 a = p[0], b = p[1];
      u32 ws[8] = {a.x, a.y, a.z, a.w, b.x, b.y, b.z, b.w};
      #pragma unroll
      for (int j = 0; j < 32; ++j)
        if ((ws[j >> 2] >> ((j & 3) * 8)) & 0xffu) w |= (1u << j);
    } else {
      const uint4* p = (const uint4*)((const u32*)maskp + off);
      #pragma unroll
      for (int q = 0; q < 8; ++q) {
        uint4 a = p[q];
        if (a.x) w |= 1u << (q * 4 + 0);
        if (a.y) w |= 1u << (q * 4 + 1);
        if (a.z) w |= 1u << (q * 4 + 2);
        if (a.w) w |= 1u << (q * 4 + 3);
      }
    }
    bmask[((size_t)(row >> 6) * 64 + (wcol >> 1)) * 128 + (row & 63) * 2 + (wcol & 1)] = w;
  }
}

// ---------------------------------------------------------- QKV GEMM -------
// 64x64 tiles (better streaming for short-K). Q,K operand-swapped -> 8-B
// stores into (B,H,T,64); V normal -> 8-B stores into (B,H,64,T).
__global__ __launch_bounds__(256) void qkv_kernel(
    const bf16* __restrict__ xb, const bf16* __restrict__ WTall,
    const float* __restrict__ bq, const float* __restrict__ bk,
    const float* __restrict__ bv,
    bf16* __restrict__ Qb, bf16* __restrict__ Kb, bf16* __restrict__ Vtb)
{
  __shared__ char smem[16384];
  char* smX = smem;
  char* smW = smem + 8192;
  int tid = threadIdx.x;
  int lane = tid & 63, wave = tid >> 6;
  int lo = lane & 15, quad = lane >> 4;
  int wr = wave >> 1, wc = wave & 1;
  int bm = blockIdx.x * 64;
  int bn = blockIdx.y * 64;
  int sel = bn >> 9;   // 0=Q 1=K 2=V
  f32x4 acc[2][2] = {};
  for (int kc = 0; kc < 8; ++kc) {
    __syncthreads();
    for (int s = tid; s < 512; s += 256) {
      int row = s >> 3, slot = s & 7;
      int cg = slot ^ (row & 7) ^ ((row >> 3) & 1);
      async16(smX + s * 16, xb + (size_t)(bm + row) * 512 + kc * 64 + cg * 8);
      async16(smW + s * 16, WTall + (size_t)(bn + row) * 512 + kc * 64 + cg * 8);
    }
    __syncthreads();
    #pragma unroll
    for (int ks = 0; ks < 2; ++ks) {
      bf16x8_t a[2], b[2];
      #pragma unroll
      for (int mt = 0; mt < 2; ++mt) {
        int row = wr * 32 + mt * 16 + lo;
        int ch = (ks * 4 + quad) ^ (row & 7) ^ ((row >> 3) & 1);
        a[mt] = *(const bf16x8_t*)(smX + row * 128 + ch * 16);
      }
      #pragma unroll
      for (int nt = 0; nt < 2; ++nt) {
        int row = wc * 32 + nt * 16 + lo;
        int ch = (ks * 4 + quad) ^ (row & 7) ^ ((row >> 3) & 1);
        b[nt] = *(const bf16x8_t*)(smW + row * 128 + ch * 16);
      }
      if (sel < 2) {
        #pragma unroll
        for (int mt = 0; mt < 2; ++mt)
          #pragma unroll
          for (int nt = 0; nt < 2; ++nt)
            acc[mt][nt] = __builtin_amdgcn_mfma_f32_16x16x32_bf16(
                b[nt], a[mt], acc[mt][nt], 0, 0, 0);   // D: m=W-row, n=t
      } else {
        #pragma unroll
        for (int mt = 0; mt < 2; ++mt)
          #pragma unroll
          for (int nt = 0; nt < 2; ++nt)
            acc[mt][nt] = __builtin_amdgcn_mfma_f32_16x16x32_bf16(
                a[mt], b[nt], acc[mt][nt], 0, 0, 0);   // D: m=t, n=W-row
      }
    }
  }
  int b_ = bm >> 12;
  if (sel < 2) {
    const float* bias = (sel == 0) ? bq : bk;
    bf16* base = (sel == 0) ? Qb : Kb;
    #pragma unroll
    for (int mt = 0; mt < 2; ++mt) {
      int t = (bm & 4095) + wr * 32 + mt * 16 + lo;
      #pragma unroll
      for (int nt = 0; nt < 2; ++nt) {
        int n0 = (bn + wc * 32 + nt * 16 + quad * 4) & 511;
        int h = n0 >> 6, dh0 = n0 & 63;
        bf16x4_t v;
        #pragma unroll
        for (int r = 0; r < 4; ++r) {
          float bs = bias[n0 + r];
          if (sel == 0) bs *= QSCALE;
          v[r] = (bf16)(acc[mt][nt][r] + bs);
        }
        *(bf16x4_t*)(base + (size_t)(b_ * H_ + h) * T_ * DH_ +
                     (size_t)t * 64 + dh0) = v;
      }
    }
  } else {
    #pragma unroll
    for (int nt = 0; nt < 2; ++nt) {
      int n0 = (bn + wc * 32 + nt * 16 + lo) & 511;
      int h = n0 >> 6, dh = n0 & 63;
      float bs = bv[n0];
      #pragma unroll
      for (int mt = 0; mt < 2; ++mt) {
        int t0 = (bm & 4095) + wr * 32 + mt * 16 + quad * 4;
        bf16x4_t v;
        #pragma unroll
        for (int r = 0; r < 4; ++r) v[r] = (bf16)(acc[mt][nt][r] + bs);
        *(bf16x4_t*)(Vtb + ((size_t)(b_ * H_ + h) * DH_ + dh) * T_ + t0) = v;
      }
    }
  }
}

// ------------------------------------------------------ flash attention ----
// one WG per (b,h, 64-row q-tile); wave (qh,kh) = 32q x 32k.
// 128 keys staged per barrier pair; two 64-key compute halves.
// S^T = mfma(K,Q); C-layout == A-frag of 16x16x16 MFMA -> PV from registers.
// Row sums on the MFMA pipe via ones-column B-fragment.
__global__ __launch_bounds__(256, 4) void attn_kernel(
    const bf16* __restrict__ Qb, const bf16* __restrict__ Kb,
    const bf16* __restrict__ Vtb, const u32* __restrict__ bm2,
    bf16* __restrict__ Obuf)
{
  __shared__ char smem[34304];
  char* smK = smem;                     // 16384: 128 key-rows x 128B
  char* smV = smem + 16384;             // 16384: 64 d-rows x 256B
  u32* smM = (u32*)(smem + 32768);      // 1024B: 256 mask words (2 kc)
  float* smLa = (float*)(smem + 33792); // 256B rowsum partials kh=0
  float* smLb = (float*)(smem + 34048); // 256B rowsum partials kh=1
  int tid = threadIdx.x;
  int lane = tid & 63, wave = tid >> 6;
  int lo = lane & 15, quad = lane >> 4;
  int qh = wave & 1, kh = wave >> 1;
  int bh = blockIdx.x >> 6;
  int qt64 = blockIdx.x & 63;
  int qbase = qt64 * 64;

  // preload Q fragments (loop-invariant); B operand of mfma(K,Q)
  const bf16* Qg = Qb + ((size_t)bh * T_ + qbase + qh * 32) * DH_;
  bf16x8_t qf[2][2];
  #pragma unroll
  for (int qt = 0; qt < 2; ++qt)
    #pragma unroll
    for (int ks = 0; ks < 2; ++ks)
      qf[qt][ks] = *(const bf16x8_t*)(Qg + (qt * 16 + lo) * 64 + ks * 32 + quad * 8);

  // ones-column B-frag for rowsum MFMA
  short one = (lo == 0) ? (short)0x3F80 : (short)0;
  short4_t ones = {one, one, one, one};

  f32x4 O[2][4] = {};
  f32x4 Ol[2] = {};

  const bf16* Kg = Kb + (size_t)bh * T_ * DH_;
  const bf16* Vg = Vtb + (size_t)bh * DH_ * T_;
  const u32* mg = bm2 + (size_t)qt64 * 8192;

  for (int kc2 = 0; kc2 < 32; ++kc2) {
    int kbase = kc2 * 128;
    __syncthreads();
    #pragma unroll
    for (int i = 0; i < 4; ++i) {
      int s = tid + i * 256;
      int row = s >> 3, slot = s & 7;
      int cg = slot ^ (row & 7) ^ ((row >> 3) & 1);
      async16(smK + s * 16, Kg + (size_t)(kbase + row) * 64 + cg * 8);
      int vrow = s >> 4, hh = (s >> 3) & 1;
      int cgv = slot ^ (vrow & 7) ^ ((vrow >> 3) & 1);
      async16(smV + s * 16, Vg + (size_t)vrow * T_ + kbase + hh * 64 + cgv * 8);
    }
    if (tid < 64) async16((char*)smM + tid * 16, mg + kc2 * 256 + tid * 4);
    __syncthreads();
    #pragma unroll
    for (int h = 0; h < 2; ++h) {
      // S^T = K Q^T (32k x 32q per wave)
      f32x4 St[2][2] = {};
      #pragma unroll
      for (int ks = 0; ks < 2; ++ks)
        #pragma unroll
        for (int kt = 0; kt < 2; ++kt) {
          int krow = h * 64 + kh * 32 + kt * 16 + lo;
          int ch = (ks * 4 + quad) ^ (krow & 7) ^ ((krow >> 3) & 1);
          bf16x8_t kf = *(const bf16x8_t*)(smK + krow * 128 + ch * 16);
          #pragma unroll
          for (int qt = 0; qt < 2; ++qt)
            St[kt][qt] = __builtin_amdgcn_mfma_f32_16x16x32_bf16(
                kf, qf[qt][ks], St[kt][qt], 0, 0, 0);
        }
      // mask (sext bitfield + AND) + exp2 + pack to PV A-frags
      short4_t pf[2][2];   // [qt][kt]
      #pragma unroll
      for (int qt = 0; qt < 2; ++qt) {
        u32 w = smM[h * 128 + (qh * 32 + qt * 16 + lo) * 2 + kh] >> (quad * 4);
        #pragma unroll
        for (int kt = 0; kt < 2; ++kt) {
          bf16x4_t t;
          #pragma unroll
          for (int r = 0; r < 4; ++r) {
            int mb = ((int)(w << (31 - (kt * 16 + r)))) >> 31;
            u32 pe = __builtin_bit_cast(u32, __builtin_amdgcn_exp2f(St[kt][qt][r]));
            t[r] = (bf16)__builtin_bit_cast(float, pe & (u32)mb);
          }
          pf[qt][kt] = __builtin_bit_cast(short4_t, t);
        }
      }
      // rowsum via ones-column
      #pragma unroll
      for (int kt = 0; kt < 2; ++kt)
        #pragma unroll
        for (int qt = 0; qt < 2; ++qt)
          Ol[qt] = __builtin_amdgcn_mfma_f32_16x16x16bf16_1k(
              pf[qt][kt], ones, Ol[qt], 0, 0, 0);
      // O += P V
      #pragma unroll
      for (int dt = 0; dt < 4; ++dt) {
        int d = dt * 16 + lo;
        #pragma unroll
        for (int kt = 0; kt < 2; ++kt) {
          int g = kh * 4 + kt * 2 + (quad >> 1);
          int c = g ^ (d & 7) ^ ((d >> 3) & 1);
          short4_t vf = *(const short4_t*)(
              smV + d * 256 + h * 128 + c * 16 + ((quad & 1) << 3));
          #pragma unroll
          for (int qt = 0; qt < 2; ++qt)
            O[qt][dt] = __builtin_amdgcn_mfma_f32_16x16x16bf16_1k(
                pf[qt][kt], vf, O[qt][dt], 0, 0, 0);
        }
      }
    }
  }
  // ---- epilogue: rowsums in lanes lo==0 of Ol; combine kh pair ----
  __syncthreads();
  float* smO = (float*)smem;       // 64 x 64 f32 = 16 KB
  if (lo == 0) {
    float* dst = (kh == 0) ? smLa : smLb;
    #pragma unroll
    for (int qt = 0; qt < 2; ++qt)
      #pragma unroll
      for (int r = 0; r < 4; ++r)
        dst[qh * 32 + qt * 16 + quad * 4 + r] = Ol[qt][r];
  }
  if (kh == 1) {
    #pragma unroll
    for (int qt = 0; qt < 2; ++qt)
      #pragma unroll
      for (int dt = 0; dt < 4; ++dt)
        #pragma unroll
        for (int r = 0; r < 4; ++r)
          smO[(qh * 32 + qt * 16 + quad * 4 + r) * 64 + dt * 16 + lo] = O[qt][dt][r];
  }
  __syncthreads();
  if (kh == 0) {
    bf16* Og = Obuf + ((size_t)bh * T_ + qbase + qh * 32) * DH_;
    #pragma unroll
    for (int qt = 0; qt < 2; ++qt) {
      #pragma unroll
      for (int r = 0; r < 4; ++r) {
        int rl = qt * 16 + quad * 4 + r;
        float inv = 1.0f / (smLa[qh * 32 + rl] + smLb[qh * 32 + rl]);
        #pragma unroll
        for (int dt = 0; dt < 4; ++dt) {
          float o = (O[qt][dt][r] + smO[(qh * 32 + rl) * 64 + dt * 16 + lo]) * inv;
          Og[(size_t)rl * 64 + dt * 16 + lo] = (bf16)o;
        }
      }
    }
  }
}

// ------------------------------------------------------ output proj --------
// 64x64 tiles, operand-swapped -> float4 stores.
__global__ __launch_bounds__(256) void proj_kernel(
    const bf16* __restrict__ Obuf, const bf16* __restrict__ WoT,
    const float* __restrict__ bo, float* __restrict__ out)
{
  __shared__ char smem[16384];
  char* smA = smem;
  char* smW = smem + 8192;
  int tid = threadIdx.x;
  int lane = tid & 63, wave = tid >> 6;
  int lo = lane & 15, quad = lane >> 4;
  int wr = wave >> 1, wc = wave & 1;
  int bm = blockIdx.x * 64;
  int bn = blockIdx.y * 64;
  int b_ = bm >> 12, trow = bm & 4095;
  f32x4 acc[2][2] = {};
  for (int kc = 0; kc < 8; ++kc) {
    __syncthreads();
    const bf16* Ag = Obuf + ((size_t)(b_ * H_ + kc) * T_ + trow) * DH_;
    for (int s = tid; s < 512; s += 256) {
      int row = s >> 3, slot = s & 7;
      int cg = slot ^ (row & 7) ^ ((row >> 3) & 1);
      async16(smA + s * 16, Ag + row * 64 + cg * 8);
      async16(smW + s * 16, WoT + (size_t)(bn + row) * 512 + kc * 64 + cg * 8);
    }
    __syncthreads();
    #pragma unroll
    for (int ks = 0; ks < 2; ++ks) {
      bf16x8_t a[2], b[2];
      #pragma unroll
      for (int mt = 0; mt < 2; ++mt) {
        int row = wr * 32 + mt * 16 + lo;
        int ch = (ks * 4 + quad) ^ (row & 7) ^ ((row >> 3) & 1);
        a[mt] = *(const bf16x8_t*)(smA + row * 128 + ch * 16);
      }
      #pragma unroll
      for (int nt = 0; nt < 2; ++nt) {
        int row = wc * 32 + nt * 16 + lo;
        int ch = (ks * 4 + quad) ^ (row & 7) ^ ((row >> 3) & 1);
        b[nt] = *(const bf16x8_t*)(smW + row * 128 + ch * 16);
      }
      #pragma unroll
      for (int mt = 0; mt < 2; ++mt)
        #pragma unroll
        for (int nt = 0; nt < 2; ++nt)
          acc[mt][nt] = __builtin_amdgcn_mfma_f32_16x16x32_bf16(
              b[nt], a[mt], acc[mt][nt], 0, 0, 0);   // D: m=out-col, n=t
    }
  }
  #pragma unroll
  for (int mt = 0; mt < 2; ++mt) {
    int t = bm + wr * 32 + mt * 16 + lo;
    #pragma unroll
    for (int nt = 0; nt < 2; ++nt) {
      int c0 = bn + wc * 32 + nt * 16 + quad * 4;
      float4 v;
      v.x = acc[mt][nt][0] + bo[c0 + 0];
      v.y = acc[mt][nt][1] + bo[c0 + 1];
      v.z = acc[mt][nt][2] + bo[c0 + 2];
      v.w = acc[mt][nt][3] + bo[c0 + 3];
      *(float4*)(out + (size_t)t * 512 + c0) = v;
    }
  }
}

// --------------------------------------------------------------- launch ----
extern "C" void kernel_launch(void* const* d_in, const int* in_sizes, int n_in,
                              void* d_out, int out_size, void* d_ws, size_t ws_size,
                              hipStream_t stream) {
  const float* x  = (const float*)d_in[0];
  const float* Wq = (const float*)d_in[1];
  const float* bq = (const float*)d_in[2];
  const float* Wk = (const float*)d_in[3];
  const float* bk = (const float*)d_in[4];
  const float* Wv = (const float*)d_in[5];
  const float* bv = (const float*)d_in[6];
  const float* Wo = (const float*)d_in[7];
  const float* bo = (const float*)d_in[8];
  const void* maskp = d_in[9];
  float* out = (float*)d_out;

  char* w = (char*)d_ws;
  bf16* xb    = (bf16*)(w);              //  8,388,608 B
  bf16* WTall = (bf16*)(w + 8388608);    //  1,572,864 B
  bf16* WoT   = (bf16*)(w + 9961472);    //    524,288 B
  bf16* Qb    = (bf16*)(w + 10485760);   //  8,388,608 B
  bf16* Kb    = (bf16*)(w + 18874368);   //  8,388,608 B
  bf16* Vtb   = (bf16*)(w + 27262976);   //  8,388,608 B  (B,H,64,T)
  bf16* Obuf  = (bf16*)(w + 35651584);   //  8,388,608 B
  u32*  bmask = (u32*)(w + 44040192);    //  2,097,152 B

  prep_kernel<<<10240, 256, 0, stream>>>(x, Wq, Wk, Wv, Wo, maskp,
                                         xb, WTall, WoT, bmask);
  qkv_kernel<<<dim3(128, 24), 256, 0, stream>>>(xb, WTall, bq, bk, bv,
                                                Qb, Kb, Vtb);
  attn_kernel<<<1024, 256, 0, stream>>>(Qb, Kb, Vtb, bmask, Obuf);
  proj_kernel<<<dim3(128, 8), 256, 0, stream>>>(Obuf, WoT, bo, out);
}

// Round 7
// 274.993 us; speedup vs baseline: 1.2669x; 1.2669x over previous
//
#include <hip/hip_runtime.h>
#include <stdint.h>

#define B_ 2
#define T_ 4096
#define D_ 512
#define H_ 8
#define DH_ 64

typedef __bf16 bf16;
typedef __bf16 bf16x4_t __attribute__((ext_vector_type(4)));
typedef __bf16 bf16x8_t __attribute__((ext_vector_type(8)));
typedef float f32x4 __attribute__((ext_vector_type(4)));
typedef short short4_t __attribute__((ext_vector_type(4)));
typedef uint32_t u32;

static constexpr float QSCALE = 0.18033688011112042f;   // log2(e)/8 (folded into Wq,bq)

__device__ __forceinline__ void async16(void* lds, const void* g) {
  __builtin_amdgcn_global_load_lds(
      (const __attribute__((address_space(1))) void*)g,
      (__attribute__((address_space(3))) void*)lds, 16, 0, 0);
}

// ---------------------------------------------------------------- prep ----
__global__ __launch_bounds__(256) void prep_kernel(
    const float* __restrict__ x,
    const float* __restrict__ Wq, const float* __restrict__ Wk,
    const float* __restrict__ Wv, const float* __restrict__ Wo,
    const void* __restrict__ maskp,
    bf16* __restrict__ xb, bf16* __restrict__ WTall, bf16* __restrict__ WoT,
    u32* __restrict__ bmask)
{
  int bid = blockIdx.x;
  int tid = threadIdx.x;
  if (bid < 4096) {
    int idx = bid * 256 + tid;
    const float4* xf = (const float4*)x;
    float4 v = xf[idx];
    bf16x4_t o;
    o[0] = (bf16)v.x; o[1] = (bf16)v.y; o[2] = (bf16)v.z; o[3] = (bf16)v.w;
    ((bf16x4_t*)xb)[idx] = o;
  } else if (bid < 8192) {
    int gid = (bid - 4096) * 256 + tid;
    int sel = gid >> 18;
    int idx = gid & 262143;
    int n = idx >> 9, k = idx & 511;
    if (sel < 3) {
      const float* W = (sel == 0) ? Wq : (sel == 1) ? Wk : Wv;
      float v = W[k * 512 + n];
      if (sel == 0) v *= QSCALE;
      WTall[gid] = (bf16)v;
    } else {
      WoT[idx] = (bf16)Wo[k * 512 + n];
    }
  } else {
    int wid = (bid - 8192) * 256 + tid;   // 524,288 words
    const uint8_t* m8 = (const uint8_t*)maskp;
    bool u8mode = (__ballot(m8[4 * (tid & 63) + 1] != 0) != 0ull);
    int row = wid >> 7, wcol = wid & 127;
    size_t off = (size_t)row * 4096 + (size_t)wcol * 32;
    u32 w = 0;
    if (u8mode) {
      const uint4* p = (const uint4*)(m8 + off);
      uint4 a = p[0], b = p[1];
      u32 ws[8] = {a.x, a.y, a.z, a.w, b.x, b.y, b.z, b.w};
      #pragma unroll
      for (int j = 0; j < 32; ++j)
        if ((ws[j >> 2] >> ((j & 3) * 8)) & 0xffu) w |= (1u << j);
    } else {
      const uint4* p = (const uint4*)((const u32*)maskp + off);
      #pragma unroll
      for (int q = 0; q < 8; ++q) {
        uint4 a = p[q];
        if (a.x) w |= 1u << (q * 4 + 0);
        if (a.y) w |= 1u << (q * 4 + 1);
        if (a.z) w |= 1u << (q * 4 + 2);
        if (a.w) w |= 1u << (q * 4 + 3);
      }
    }
    bmask[((size_t)(row >> 6) * 64 + (wcol >> 1)) * 128 + (row & 63) * 2 + (wcol & 1)] = w;
  }
}

// ---------------------------------------------------------- QKV GEMM -------
// 64x64 tiles. Q,K operand-swapped -> 8-B stores into (B,H,T,64);
// V normal -> 8-B stores into (B,H,64,T).
__global__ __launch_bounds__(256) void qkv_kernel(
    const bf16* __restrict__ xb, const bf16* __restrict__ WTall,
    const float* __restrict__ bq, const float* __restrict__ bk,
    const float* __restrict__ bv,
    bf16* __restrict__ Qb, bf16* __restrict__ Kb, bf16* __restrict__ Vtb)
{
  __shared__ char smem[16384];
  char* smX = smem;
  char* smW = smem + 8192;
  int tid = threadIdx.x;
  int lane = tid & 63, wave = tid >> 6;
  int lo = lane & 15, quad = lane >> 4;
  int wr = wave >> 1, wc = wave & 1;
  int bm = blockIdx.x * 64;
  int bn = blockIdx.y * 64;
  int sel = bn >> 9;   // 0=Q 1=K 2=V
  f32x4 acc[2][2] = {};
  for (int kc = 0; kc < 8; ++kc) {
    __syncthreads();
    for (int s = tid; s < 512; s += 256) {
      int row = s >> 3, slot = s & 7;
      int cg = slot ^ (row & 7) ^ ((row >> 3) & 1);
      async16(smX + s * 16, xb + (size_t)(bm + row) * 512 + kc * 64 + cg * 8);
      async16(smW + s * 16, WTall + (size_t)(bn + row) * 512 + kc * 64 + cg * 8);
    }
    __syncthreads();
    #pragma unroll
    for (int ks = 0; ks < 2; ++ks) {
      bf16x8_t a[2], b[2];
      #pragma unroll
      for (int mt = 0; mt < 2; ++mt) {
        int row = wr * 32 + mt * 16 + lo;
        int ch = (ks * 4 + quad) ^ (row & 7) ^ ((row >> 3) & 1);
        a[mt] = *(const bf16x8_t*)(smX + row * 128 + ch * 16);
      }
      #pragma unroll
      for (int nt = 0; nt < 2; ++nt) {
        int row = wc * 32 + nt * 16 + lo;
        int ch = (ks * 4 + quad) ^ (row & 7) ^ ((row >> 3) & 1);
        b[nt] = *(const bf16x8_t*)(smW + row * 128 + ch * 16);
      }
      if (sel < 2) {
        #pragma unroll
        for (int mt = 0; mt < 2; ++mt)
          #pragma unroll
          for (int nt = 0; nt < 2; ++nt)
            acc[mt][nt] = __builtin_amdgcn_mfma_f32_16x16x32_bf16(
                b[nt], a[mt], acc[mt][nt], 0, 0, 0);   // D: m=W-row, n=t
      } else {
        #pragma unroll
        for (int mt = 0; mt < 2; ++mt)
          #pragma unroll
          for (int nt = 0; nt < 2; ++nt)
            acc[mt][nt] = __builtin_amdgcn_mfma_f32_16x16x32_bf16(
                a[mt], b[nt], acc[mt][nt], 0, 0, 0);   // D: m=t, n=W-row
      }
    }
  }
  int b_ = bm >> 12;
  if (sel < 2) {
    const float* bias = (sel == 0) ? bq : bk;
    bf16* base = (sel == 0) ? Qb : Kb;
    #pragma unroll
    for (int mt = 0; mt < 2; ++mt) {
      int t = (bm & 4095) + wr * 32 + mt * 16 + lo;
      #pragma unroll
      for (int nt = 0; nt < 2; ++nt) {
        int n0 = (bn + wc * 32 + nt * 16 + quad * 4) & 511;
        int h = n0 >> 6, dh0 = n0 & 63;
        bf16x4_t v;
        #pragma unroll
        for (int r = 0; r < 4; ++r) {
          float bs = bias[n0 + r];
          if (sel == 0) bs *= QSCALE;
          v[r] = (bf16)(acc[mt][nt][r] + bs);
        }
        *(bf16x4_t*)(base + (size_t)(b_ * H_ + h) * T_ * DH_ +
                     (size_t)t * 64 + dh0) = v;
      }
    }
  } else {
    #pragma unroll
    for (int nt = 0; nt < 2; ++nt) {
      int n0 = (bn + wc * 32 + nt * 16 + lo) & 511;
      int h = n0 >> 6, dh = n0 & 63;
      float bs = bv[n0];
      #pragma unroll
      for (int mt = 0; mt < 2; ++mt) {
        int t0 = (bm & 4095) + wr * 32 + mt * 16 + quad * 4;
        bf16x4_t v;
        #pragma unroll
        for (int r = 0; r < 4; ++r) v[r] = (bf16)(acc[mt][nt][r] + bs);
        *(bf16x4_t*)(Vtb + ((size_t)(b_ * H_ + h) * DH_ + dh) * T_ + t0) = v;
      }
    }
  }
}

// ------------------------------------------------------ flash attention ----
// one WG per (b,h, 64-row q-tile); wave (qh,kh) = 32q x 32k; 64-key chunks,
// two-barrier single-buffer staging (proven structure).
// XCD-aware bh binding: bh = blk&15 -> each XCD serves 2 bh (K/V fit its L2).
// S^T = mfma(K,Q); C-layout == A-frag of 16x16x16 MFMA -> PV from registers.
// Row sums on the MFMA pipe via ones-column B-fragment.
__global__ __launch_bounds__(256, 4) void attn_kernel(
    const bf16* __restrict__ Qb, const bf16* __restrict__ Kb,
    const bf16* __restrict__ Vtb, const u32* __restrict__ bm2,
    bf16* __restrict__ Obuf)
{
  __shared__ char smem[17408];
  char* smK = smem;                     // 8192: 64 key-rows x 128B (swizzled)
  char* smV = smem + 8192;              // 8192: 64 d-rows x 128B (swizzled)
  u32* smM = (u32*)(smem + 16384);      // 512B mask words
  float* smLa = (float*)(smem + 16896); // 256B rowsum partials kh=0
  float* smLb = (float*)(smem + 17152); // 256B rowsum partials kh=1
  int tid = threadIdx.x;
  int lane = tid & 63, wave = tid >> 6;
  int lo = lane & 15, quad = lane >> 4;
  int qh = wave & 1, kh = wave >> 1;
  int blk = blockIdx.x;
  int bh = blk & 15;                    // XCD-aware: bh pinned per XCD
  int qt64 = blk >> 4;
  int qbase = qt64 * 64;

  const bf16* Kg = Kb + (size_t)bh * T_ * DH_;
  const bf16* Vg = Vtb + (size_t)bh * DH_ * T_;
  const u32* mg = bm2 + (size_t)qt64 * 8192;

  // preload Q fragments (loop-invariant); B operand of mfma(K,Q)
  const bf16* Qg = Qb + ((size_t)bh * T_ + qbase + qh * 32) * DH_;
  bf16x8_t qf[2][2];
  #pragma unroll
  for (int qt = 0; qt < 2; ++qt)
    #pragma unroll
    for (int ks = 0; ks < 2; ++ks)
      qf[qt][ks] = *(const bf16x8_t*)(Qg + (qt * 16 + lo) * 64 + ks * 32 + quad * 8);

  // ones-column B-frag for rowsum MFMA
  short one = (lo == 0) ? (short)0x3F80 : (short)0;
  short4_t ones = {one, one, one, one};

  f32x4 O[2][4] = {};
  f32x4 Ol[2] = {};

  for (int kc = 0; kc < 64; ++kc) {
    __syncthreads();                    // prior compute done: safe to restage
    #pragma unroll
    for (int i = 0; i < 2; ++i) {
      int s = tid + i * 256;
      int row = s >> 3, slot = s & 7;
      int cg = slot ^ (row & 7) ^ ((row >> 3) & 1);
      async16(smK + s * 16, Kg + (size_t)(kc * 64 + row) * 64 + cg * 8);
      async16(smV + s * 16, Vg + (size_t)row * T_ + kc * 64 + cg * 8);
    }
    if (tid < 32) async16((char*)smM + tid * 16, mg + kc * 128 + tid * 4);
    __syncthreads();                    // staging visible
    // S^T = K Q^T (32k x 32q per wave)
    f32x4 St[2][2] = {};
    #pragma unroll
    for (int ks = 0; ks < 2; ++ks)
      #pragma unroll
      for (int kt = 0; kt < 2; ++kt) {
        int krow = kh * 32 + kt * 16 + lo;
        int ch = (ks * 4 + quad) ^ (krow & 7) ^ ((krow >> 3) & 1);
        bf16x8_t kf = *(const bf16x8_t*)(smK + krow * 128 + ch * 16);
        #pragma unroll
        for (int qt = 0; qt < 2; ++qt)
          St[kt][qt] = __builtin_amdgcn_mfma_f32_16x16x32_bf16(
              kf, qf[qt][ks], St[kt][qt], 0, 0, 0);
      }
    // mask (sext bitfield + AND) + exp2 + pack to PV A-frags
    short4_t pf[2][2];   // [qt][kt]
    #pragma unroll
    for (int qt = 0; qt < 2; ++qt) {
      u32 w = smM[(qh * 32 + qt * 16 + lo) * 2 + kh] >> (quad * 4);
      #pragma unroll
      for (int kt = 0; kt < 2; ++kt) {
        bf16x4_t t;
        #pragma unroll
        for (int r = 0; r < 4; ++r) {
          int mb = ((int)(w << (31 - (kt * 16 + r)))) >> 31;
          u32 pe = __builtin_bit_cast(u32, __builtin_amdgcn_exp2f(St[kt][qt][r]));
          t[r] = (bf16)__builtin_bit_cast(float, pe & (u32)mb);
        }
        pf[qt][kt] = __builtin_bit_cast(short4_t, t);
      }
    }
    // rowsum via ones-column on the MFMA pipe
    #pragma unroll
    for (int kt = 0; kt < 2; ++kt)
      #pragma unroll
      for (int qt = 0; qt < 2; ++qt)
        Ol[qt] = __builtin_amdgcn_mfma_f32_16x16x16bf16_1k(
            pf[qt][kt], ones, Ol[qt], 0, 0, 0);
    // O += P V
    #pragma unroll
    for (int dt = 0; dt < 4; ++dt) {
      int d = dt * 16 + lo;
      #pragma unroll
      for (int kt = 0; kt < 2; ++kt) {
        int c0 = kh * 4 + kt * 2 + (quad >> 1);
        int c = c0 ^ (d & 7) ^ ((d >> 3) & 1);
        short4_t vf = *(const short4_t*)(
            smV + d * 128 + c * 16 + ((quad & 1) << 3));
        #pragma unroll
        for (int qt = 0; qt < 2; ++qt)
          O[qt][dt] = __builtin_amdgcn_mfma_f32_16x16x16bf16_1k(
              pf[qt][kt], vf, O[qt][dt], 0, 0, 0);
      }
    }
  }
  // ---- epilogue: rowsums in lanes lo==0 of Ol; combine kh pair ----
  __syncthreads();
  float* smO = (float*)smem;       // 64 x 64 f32 = 16 KB (reuses smK/smV)
  if (lo == 0) {
    float* dst = (kh == 0) ? smLa : smLb;
    #pragma unroll
    for (int qt = 0; qt < 2; ++qt)
      #pragma unroll
      for (int r = 0; r < 4; ++r)
        dst[qh * 32 + qt * 16 + quad * 4 + r] = Ol[qt][r];
  }
  if (kh == 1) {
    #pragma unroll
    for (int qt = 0; qt < 2; ++qt)
      #pragma unroll
      for (int dt = 0; dt < 4; ++dt)
        #pragma unroll
        for (int r = 0; r < 4; ++r)
          smO[(qh * 32 + qt * 16 + quad * 4 + r) * 64 + dt * 16 + lo] = O[qt][dt][r];
  }
  __syncthreads();
  if (kh == 0) {
    bf16* Og = Obuf + ((size_t)bh * T_ + qbase + qh * 32) * DH_;
    #pragma unroll
    for (int qt = 0; qt < 2; ++qt) {
      #pragma unroll
      for (int r = 0; r < 4; ++r) {
        int rl = qt * 16 + quad * 4 + r;
        float inv = 1.0f / (smLa[qh * 32 + rl] + smLb[qh * 32 + rl]);
        #pragma unroll
        for (int dt = 0; dt < 4; ++dt) {
          float o = (O[qt][dt][r] + smO[(qh * 32 + rl) * 64 + dt * 16 + lo]) * inv;
          Og[(size_t)rl * 64 + dt * 16 + lo] = (bf16)o;
        }
      }
    }
  }
}

// ------------------------------------------------------ output proj --------
// 64x64 tiles, operand-swapped -> float4 stores.
__global__ __launch_bounds__(256) void proj_kernel(
    const bf16* __restrict__ Obuf, const bf16* __restrict__ WoT,
    const float* __restrict__ bo, float* __restrict__ out)
{
  __shared__ char smem[16384];
  char* smA = smem;
  char* smW = smem + 8192;
  int tid = threadIdx.x;
  int lane = tid & 63, wave = tid >> 6;
  int lo = lane & 15, quad = lane >> 4;
  int wr = wave >> 1, wc = wave & 1;
  int bm = blockIdx.x * 64;
  int bn = blockIdx.y * 64;
  int b_ = bm >> 12, trow = bm & 4095;
  f32x4 acc[2][2] = {};
  for (int kc = 0; kc < 8; ++kc) {
    __syncthreads();
    const bf16* Ag = Obuf + ((size_t)(b_ * H_ + kc) * T_ + trow) * DH_;
    for (int s = tid; s < 512; s += 256) {
      int row = s >> 3, slot = s & 7;
      int cg = slot ^ (row & 7) ^ ((row >> 3) & 1);
      async16(smA + s * 16, Ag + row * 64 + cg * 8);
      async16(smW + s * 16, WoT + (size_t)(bn + row) * 512 + kc * 64 + cg * 8);
    }
    __syncthreads();
    #pragma unroll
    for (int ks = 0; ks < 2; ++ks) {
      bf16x8_t a[2], b[2];
      #pragma unroll
      for (int mt = 0; mt < 2; ++mt) {
        int row = wr * 32 + mt * 16 + lo;
        int ch = (ks * 4 + quad) ^ (row & 7) ^ ((row >> 3) & 1);
        a[mt] = *(const bf16x8_t*)(smA + row * 128 + ch * 16);
      }
      #pragma unroll
      for (int nt = 0; nt < 2; ++nt) {
        int row = wc * 32 + nt * 16 + lo;
        int ch = (ks * 4 + quad) ^ (row & 7) ^ ((row >> 3) & 1);
        b[nt] = *(const bf16x8_t*)(smW + row * 128 + ch * 16);
      }
      #pragma unroll
      for (int mt = 0; mt < 2; ++mt)
        #pragma unroll
        for (int nt = 0; nt < 2; ++nt)
          acc[mt][nt] = __builtin_amdgcn_mfma_f32_16x16x32_bf16(
              b[nt], a[mt], acc[mt][nt], 0, 0, 0);   // D: m=out-col, n=t
    }
  }
  #pragma unroll
  for (int mt = 0; mt < 2; ++mt) {
    int t = bm + wr * 32 + mt * 16 + lo;
    #pragma unroll
    for (int nt = 0; nt < 2; ++nt) {
      int c0 = bn + wc * 32 + nt * 16 + quad * 4;
      float4 v;
      v.x = acc[mt][nt][0] + bo[c0 + 0];
      v.y = acc[mt][nt][1] + bo[c0 + 1];
      v.z = acc[mt][nt][2] + bo[c0 + 2];
      v.w = acc[mt][nt][3] + bo[c0 + 3];
      *(float4*)(out + (size_t)t * 512 + c0) = v;
    }
  }
}

// --------------------------------------------------------------- launch ----
extern "C" void kernel_launch(void* const* d_in, const int* in_sizes, int n_in,
                              void* d_out, int out_size, void* d_ws, size_t ws_size,
                              hipStream_t stream) {
  const float* x  = (const float*)d_in[0];
  const float* Wq = (const float*)d_in[1];
  const float* bq = (const float*)d_in[2];
  const float* Wk = (const float*)d_in[3];
  const float* bk = (const float*)d_in[4];
  const float* Wv = (const float*)d_in[5];
  const float* bv = (const float*)d_in[6];
  const float* Wo = (const float*)d_in[7];
  const float* bo = (const float*)d_in[8];
  const void* maskp = d_in[9];
  float* out = (float*)d_out;

  char* w = (char*)d_ws;
  bf16* xb    = (bf16*)(w);              //  8,388,608 B
  bf16* WTall = (bf16*)(w + 8388608);    //  1,572,864 B
  bf16* WoT   = (bf16*)(w + 9961472);    //    524,288 B
  bf16* Qb    = (bf16*)(w + 10485760);   //  8,388,608 B
  bf16* Kb    = (bf16*)(w + 18874368);   //  8,388,608 B
  bf16* Vtb   = (bf16*)(w + 27262976);   //  8,388,608 B  (B,H,64,T)
  bf16* Obuf  = (bf16*)(w + 35651584);   //  8,388,608 B
  u32*  bmask = (u32*)(w + 44040192);    //  2,097,152 B

  prep_kernel<<<10240, 256, 0, stream>>>(x, Wq, Wk, Wv, Wo, maskp,
                                         xb, WTall, WoT, bmask);
  qkv_kernel<<<dim3(128, 24), 256, 0, stream>>>(xb, WTall, bq, bk, bv,
                                                Qb, Kb, Vtb);
  attn_kernel<<<1024, 256, 0, stream>>>(Qb, Kb, Vtb, bmask, Obuf);
  proj_kernel<<<dim3(128, 8), 256, 0, stream>>>(Obuf, WoT, bo, out);
}